// Round 13
// baseline (575.877 us; speedup 1.0000x reference)
//
#include <hip/hip_runtime.h>
#include <hip/hip_bf16.h>

#define NN 20000
#define NE 100000
#define HID 256
#define HO 1024   // HEADS*OUT
#define HEADS 4
#define OUT 256

typedef __attribute__((ext_vector_type(8))) short bf16x8;
typedef __attribute__((ext_vector_type(4))) float f32x4;

__device__ inline ushort f2bf(float f) {
    union { float f; unsigned u; } v; v.f = f;
    unsigned r = v.u + 0x7FFFu + ((v.u >> 16) & 1u);  // RNE
    return (ushort)(r >> 16);
}
__device__ inline float bf2f(ushort b) {
    union { unsigned u; float f; } v; v.u = ((unsigned)b) << 16;
    return v.f;
}

// ---------------------------------------------------------------------------
// K1: h_bf = bf16(relu(x @ W_ne + b_ne))   x:[N,7] W:[7,256]
__global__ __launch_bounds__(256) void node_enc_kernel(
    const float* __restrict__ x, const float* __restrict__ W,
    const float* __restrict__ b, ushort* __restrict__ h)
{
    int n = blockIdx.x;
    int c = threadIdx.x;
    __shared__ float xs[8];
    if (threadIdx.x < 7) xs[threadIdx.x] = x[n * 7 + threadIdx.x];
    __syncthreads();
    float acc = b[c];
#pragma unroll
    for (int k = 0; k < 7; k++) acc += xs[k] * W[k * HID + c];
    h[(size_t)n * HID + c] = f2bf(fmaxf(acc, 0.f));
}

// ---------------------------------------------------------------------------
// WT[n][k] = bf16(W[k][n])   W:[K,N]  grid=dim3(K, N/256)
__global__ __launch_bounds__(256) void transpose_bf16_kernel(
    const float* __restrict__ W, ushort* __restrict__ WT, int K, int N)
{
    int k = blockIdx.x;
    int n = blockIdx.y * 256 + threadIdx.x;
    WT[(size_t)n * K + k] = f2bf(W[(size_t)k * N + n]);
}

// ---------------------------------------------------------------------------
// biasH[c] = b_d1[c] + sum_k conv_bias[k] * W_d1[k,c]
__global__ __launch_bounds__(256) void biasH_kernel(
    const float* __restrict__ conv_bias, const float* __restrict__ W_d1,
    const float* __restrict__ b_d1, float* __restrict__ biasH)
{
    int c = threadIdx.x;
    float acc = b_d1[c];
    for (int k = 0; k < HO; k++) acc += conv_bias[k] * W_d1[(size_t)k * HID + c];
    biasH[c] = acc;
}

// ---------------------------------------------------------------------------
// CSR build
__global__ __launch_bounds__(256) void hist_kernel(
    const int* __restrict__ ei, int* __restrict__ deg)
{
    int e = blockIdx.x * blockDim.x + threadIdx.x;
    if (e >= NE) return;
    atomicAdd(&deg[ei[NE + e]], 1);
}

__global__ __launch_bounds__(1024) void scan_kernel(
    const int* __restrict__ deg, int* __restrict__ rowptr, int* __restrict__ cursor)
{
    const int CH = 20;   // 1024*20 = 20480 >= 20000
    int t = threadIdx.x;
    int start = t * CH;
    int d[CH];
    int local = 0;
#pragma unroll
    for (int i = 0; i < CH; i++) {
        int idx = start + i;
        d[i] = (idx < NN) ? deg[idx] : 0;
        local += d[i];
    }
    int incl = local;
#pragma unroll
    for (int off = 1; off < 64; off <<= 1) {
        int v = __shfl_up(incl, off);
        if ((t & 63) >= off) incl += v;
    }
    __shared__ int waveTot[16];
    int wv = t >> 6;
    if ((t & 63) == 63) waveTot[wv] = incl;
    __syncthreads();
    if (t < 16) {
        int v = waveTot[t];
        int s = v;
#pragma unroll
        for (int off = 1; off < 16; off <<= 1) {
            int u = __shfl_up(s, off);
            if (t >= off) s += u;
        }
        waveTot[t] = s - v;
    }
    __syncthreads();
    int run = (incl - local) + waveTot[wv];
#pragma unroll
    for (int i = 0; i < CH; i++) {
        int idx = start + i;
        if (idx < NN) { rowptr[idx] = run; cursor[idx] = run; }
        run += d[i];
    }
    if (t == 1023) rowptr[NN] = run;
}

__global__ __launch_bounds__(256) void scatter_kernel(
    const int* __restrict__ ei, int* __restrict__ cursor, int* __restrict__ eidx,
    int* __restrict__ srcs, int* __restrict__ dsts)
{
    int e = blockIdx.x * blockDim.x + threadIdx.x;
    if (e >= NE) return;
    int d = ei[NE + e];
    int pos = atomicAdd(&cursor[d], 1);
    eidx[pos] = e;
    srcs[pos] = ei[e];
    dsts[pos] = d;
}

// ---------------------------------------------------------------------------
// xl/xr GEMM: C[M,1024] col-tile 256 per blockIdx.y.
__global__ __launch_bounds__(256) void qkv_gemm_kernel(
    const ushort* __restrict__ A, const ushort* __restrict__ BT,
    const float* __restrict__ bias, ushort* __restrict__ C, int M)
{
    __shared__ __align__(16) ushort As[64][264];
    int t = threadIdx.x, w = t >> 6, lane = t & 63;
    int l15 = lane & 15, l4 = lane >> 4;
    int row0 = blockIdx.x * 64;
    int colOff = blockIdx.y * 256;
    {
        int r = t >> 2, c0 = (t & 3) * 64;
        int row = row0 + r;
        if (row < M) {
            const ushort* src = &A[(size_t)row * 256 + c0];
#pragma unroll
            for (int c = 0; c < 8; c++)
                *(bf16x8*)&As[r][c0 + c * 8] = *(const bf16x8*)&src[c * 8];
        } else {
            bf16x8 z = (bf16x8){0, 0, 0, 0, 0, 0, 0, 0};
#pragma unroll
            for (int c = 0; c < 8; c++) *(bf16x8*)&As[r][c0 + c * 8] = z;
        }
    }
    __syncthreads();
    f32x4 acc[4][4] = {};
    for (int k0 = 0; k0 < 256; k0 += 32) {
        bf16x8 a[4], b[4];
#pragma unroll
        for (int rt = 0; rt < 4; rt++)
            a[rt] = *(const bf16x8*)&As[rt * 16 + l15][k0 + l4 * 8];
#pragma unroll
        for (int ct = 0; ct < 4; ct++) {
            int n = colOff + w * 64 + ct * 16 + l15;
            b[ct] = *(const bf16x8*)&BT[(size_t)n * 256 + k0 + l4 * 8];
        }
#pragma unroll
        for (int rt = 0; rt < 4; rt++)
#pragma unroll
            for (int ct = 0; ct < 4; ct++)
                acc[rt][ct] = __builtin_amdgcn_mfma_f32_16x16x32_bf16(
                    a[rt], b[ct], acc[rt][ct], 0, 0, 0);
    }
    float bv[4];
#pragma unroll
    for (int ct = 0; ct < 4; ct++) bv[ct] = bias[colOff + w * 64 + ct * 16 + l15];
#pragma unroll
    for (int rt = 0; rt < 4; rt++)
#pragma unroll
        for (int ct = 0; ct < 4; ct++)
#pragma unroll
            for (int r = 0; r < 4; r++) {
                int row = row0 + rt * 16 + l4 * 4 + r;
                if (row < M)
                    C[(size_t)row * 1024 + colOff + w * 64 + ct * 16 + l15] =
                        f2bf(acc[rt][ct][r] + bv[ct]);
            }
}

// ---------------------------------------------------------------------------
// Decoder GEMM: C[M,256] = relu(A[M,1024] @ BT[256,1024]^T + biasH), bf16 out.
__global__ __launch_bounds__(256) void dec_gemm_kernel(
    const ushort* __restrict__ A, const ushort* __restrict__ BT,
    const float* __restrict__ biasH, ushort* __restrict__ C, int M)
{
    __shared__ __align__(16) ushort As[64][264];
    int t = threadIdx.x, w = t >> 6, lane = t & 63;
    int l15 = lane & 15, l4 = lane >> 4;
    int row0 = blockIdx.x * 64;
    f32x4 acc[4][4] = {};
    for (int kc = 0; kc < 4; kc++) {
        if (kc) __syncthreads();
        {
            int r = t >> 2, c0 = (t & 3) * 64;
            int row = row0 + r;
            if (row < M) {
                const ushort* src = &A[(size_t)row * 1024 + kc * 256 + c0];
#pragma unroll
                for (int c = 0; c < 8; c++)
                    *(bf16x8*)&As[r][c0 + c * 8] = *(const bf16x8*)&src[c * 8];
            } else {
                bf16x8 z = (bf16x8){0, 0, 0, 0, 0, 0, 0, 0};
#pragma unroll
                for (int c = 0; c < 8; c++) *(bf16x8*)&As[r][c0 + c * 8] = z;
            }
        }
        __syncthreads();
        for (int k0 = 0; k0 < 256; k0 += 32) {
            bf16x8 a[4], b[4];
#pragma unroll
            for (int rt = 0; rt < 4; rt++)
                a[rt] = *(const bf16x8*)&As[rt * 16 + l15][k0 + l4 * 8];
#pragma unroll
            for (int ct = 0; ct < 4; ct++) {
                int n = w * 64 + ct * 16 + l15;
                b[ct] = *(const bf16x8*)&BT[(size_t)n * 1024 + kc * 256 + k0 + l4 * 8];
            }
#pragma unroll
            for (int rt = 0; rt < 4; rt++)
#pragma unroll
                for (int ct = 0; ct < 4; ct++)
                    acc[rt][ct] = __builtin_amdgcn_mfma_f32_16x16x32_bf16(
                        a[rt], b[ct], acc[rt][ct], 0, 0, 0);
        }
    }
    float bv[4];
#pragma unroll
    for (int ct = 0; ct < 4; ct++) bv[ct] = biasH[w * 64 + ct * 16 + l15];
#pragma unroll
    for (int rt = 0; rt < 4; rt++)
#pragma unroll
        for (int ct = 0; ct < 4; ct++)
#pragma unroll
            for (int r = 0; r < 4; r++) {
                int row = row0 + rt * 16 + l4 * 4 + r;
                if (row < M)
                    C[(size_t)row * 256 + w * 64 + ct * 16 + l15] =
                        f2bf(fmaxf(acc[rt][ct][r] + bv[ct], 0.f));
            }
}

// ---------------------------------------------------------------------------
// Fused edge kernel, ALL HEADS, software-pipelined gathers:
// head h's xl/xr row-loads are issued one iteration early (h=0 before e_enc),
// so ~2000+ cy of e_enc/MFMA/logits hide the L3 gather latency; the LDS write
// of landed registers is cheap.
#define EPB 32
__global__ __launch_bounds__(256, 4) void edge_mfma_logits_kernel(
    const float* __restrict__ edge_attr, const float* __restrict__ W_ee,
    const float* __restrict__ b_ee, const ushort* __restrict__ WeT,
    const float* __restrict__ b_e, const float* __restrict__ att,
    const ushort* __restrict__ xl, const ushort* __restrict__ xr,
    const int* __restrict__ eidx, const int* __restrict__ srcs,
    const int* __restrict__ dsts, float* __restrict__ lbuf4)
{
    __shared__ __align__(16) ushort As[EPB][264];    // e_enc, 16.9 KB
    __shared__ __align__(16) ushort XLR[64][264];    // 32 XL + 32 XR rows, 33.8 KB
    __shared__ float ea[EPB * 7];
    __shared__ int sArr[EPB], dArr[EPB];
    __shared__ float red[4][EPB];
    int j0 = blockIdx.x * EPB;
    int t = threadIdx.x, w = t >> 6, lane = t & 63;
    int l15 = lane & 15, l4 = lane >> 4;

    if (t < EPB * 7) {
        int e = eidx[j0 + t / 7];
        ea[t] = edge_attr[(size_t)e * 7 + t % 7];
    }
    if (t < EPB) {
        sArr[t] = srcs[j0 + t];
        dArr[t] = dsts[j0 + t];
    }
    __syncthreads();

    // per-thread gather base (row fixed per block); head offset varies
    int gr = t >> 2;            // staging row 0..63 (0-31 XL, 32-63 XR)
    int gc = (t & 3) * 64;      // col chunk: 64 ushorts = 128 B
    int eIdx = gr & 31;
    const ushort* gbase = (gr < 32)
        ? &xl[(size_t)sArr[eIdx] * 1024 + gc]
        : &xr[(size_t)dArr[eIdx] * 1024 + gc];

    // ---- prefetch head 0 gathers (latency hides under e_enc + MFMA(0)) ----
    bf16x8 pf[8];
#pragma unroll
    for (int c = 0; c < 8; c++) pf[c] = *(const bf16x8*)&gbase[c * 8];

    // ---- phase A: e_enc once ----
    {
        float w7[7];
#pragma unroll
        for (int k = 0; k < 7; k++) w7[k] = W_ee[k * HID + t];
        float bee = b_ee[t];
#pragma unroll 4
        for (int r = 0; r < EPB; r++) {
            float acc = bee;
#pragma unroll
            for (int k = 0; k < 7; k++) acc += w7[k] * ea[r * 7 + k];
            As[r][t] = f2bf(fmaxf(acc, 0.f));
        }
    }
    __syncthreads();

    for (int h = 0; h < HEADS; h++) {
        // ---- MFMA for head h ----
        f32x4 acc[2][4] = {};
        for (int k0 = 0; k0 < 256; k0 += 32) {
            bf16x8 a[2], b[4];
#pragma unroll
            for (int rt = 0; rt < 2; rt++)
                a[rt] = *(const bf16x8*)&As[rt * 16 + l15][k0 + l4 * 8];
#pragma unroll
            for (int ct = 0; ct < 4; ct++) {
                int n = h * 256 + w * 64 + ct * 16 + l15;
                b[ct] = *(const bf16x8*)&WeT[(size_t)n * 256 + k0 + l4 * 8];
            }
#pragma unroll
            for (int rt = 0; rt < 2; rt++)
#pragma unroll
                for (int ct = 0; ct < 4; ct++)
                    acc[rt][ct] = __builtin_amdgcn_mfma_f32_16x16x32_bf16(
                        a[rt], b[ct], acc[rt][ct], 0, 0, 0);
        }

        // ---- write landed prefetch regs -> XLR (XLR free: prev logits done) ----
#pragma unroll
        for (int c = 0; c < 8; c++)
            *(bf16x8*)&XLR[gr][gc + c * 8] = pf[c];

        // ---- issue next head's gathers (hide under logits(h) + MFMA(h+1)) ----
        if (h + 1 < HEADS) {
#pragma unroll
            for (int c = 0; c < 8; c++)
                pf[c] = *(const bf16x8*)&gbase[(h + 1) * 256 + c * 8];
        }

        float bev[4], atv[4];
#pragma unroll
        for (int ct = 0; ct < 4; ct++) {
            int col = w * 64 + ct * 16 + l15;
            bev[ct] = b_e[h * 256 + col];
            atv[ct] = att[h * 256 + col];
        }
        __syncthreads();   // (1) XLR writes visible

        // ---- logits for both 16-edge groups ----
        float lp[2][4];
#pragma unroll
        for (int rt = 0; rt < 2; rt++)
#pragma unroll
            for (int r = 0; r < 4; r++) {
                int li = rt * 16 + l4 * 4 + r;
                float p = 0.f;
#pragma unroll
                for (int ct = 0; ct < 4; ct++) {
                    int col = w * 64 + ct * 16 + l15;
                    float z = acc[rt][ct][r] + bev[ct] +
                              bf2f(XLR[li][col]) + bf2f(XLR[32 + li][col]);
                    z = (z > 0.f) ? z : 0.2f * z;
                    p += z * atv[ct];
                }
                lp[rt][r] = p;
            }
#pragma unroll
        for (int off = 1; off < 16; off <<= 1)
#pragma unroll
            for (int rt = 0; rt < 2; rt++)
#pragma unroll
                for (int r = 0; r < 4; r++)
                    lp[rt][r] += __shfl_xor(lp[rt][r], off);
        if (l15 == 0)
#pragma unroll
            for (int rt = 0; rt < 2; rt++)
#pragma unroll
                for (int r = 0; r < 4; r++)
                    red[w][rt * 16 + l4 * 4 + r] = lp[rt][r];
        __syncthreads();   // (2) red complete; XLR reads complete

        if (t < EPB) {
            float v = red[0][t] + red[1][t] + red[2][t] + red[3][t];
            lbuf4[(size_t)(j0 + t) * 4 + h] = v;
        }
        // red(h+1) writes happen after barrier (1) of h+1 => lbuf read safe
    }
}

// ---------------------------------------------------------------------------
// Fused segment softmax + aggregation, ALL HEADS: block = node, wave = head.
__global__ __launch_bounds__(256) void softmax_agg_kernel(
    const float* __restrict__ lbuf4, const int* __restrict__ rowptr,
    const int* __restrict__ srcs, const ushort* __restrict__ xl,
    ushort* __restrict__ agg)
{
    int n = blockIdx.x;
    int h = threadIdx.x >> 6, lane = threadIdx.x & 63;
    int r0 = rowptr[n], r1 = rowptr[n + 1];
    float m = -3.4e38f;
    for (int j = r0; j < r1; j++)
        m = fmaxf(m, lbuf4[(size_t)j * 4 + h]);
    float denom = 0.f;
    for (int j = r0; j < r1; j++)
        denom += __expf(lbuf4[(size_t)j * 4 + h] - m);
    float rd = (denom > 0.f) ? 1.f / denom : 0.f;
    float a0 = 0.f, a1 = 0.f, a2 = 0.f, a3 = 0.f;
    for (int j = r0; j < r1; j++) {
        int s = srcs[j];
        float alpha = __expf(lbuf4[(size_t)j * 4 + h] - m) * rd;
        ushort4 xv = *(const ushort4*)&xl[(size_t)s * 1024 + h * 256 + lane * 4];
        a0 += alpha * bf2f(xv.x); a1 += alpha * bf2f(xv.y);
        a2 += alpha * bf2f(xv.z); a3 += alpha * bf2f(xv.w);
    }
    ushort4 o;
    o.x = f2bf(a0); o.y = f2bf(a1); o.z = f2bf(a2); o.w = f2bf(a3);
    *(ushort4*)&agg[(size_t)n * 1024 + h * 256 + lane * 4] = o;
}

// ---------------------------------------------------------------------------
// out = sigmoid(hid_bf @ W_d2 + b_d2)   hid:[N,256] bf16, W:[256,6]
__global__ __launch_bounds__(256) void final_kernel(
    const ushort* __restrict__ hid, const float* __restrict__ W_d2,
    const float* __restrict__ b_d2, float* __restrict__ out)
{
    int g = blockIdx.x * blockDim.x + threadIdx.x;
    if (g >= NN * 6) return;
    int n = g / 6, j = g % 6;
    float acc = b_d2[j];
    const bf16x8* hp = reinterpret_cast<const bf16x8*>(&hid[(size_t)n * HID]);
#pragma unroll 4
    for (int k8 = 0; k8 < HID / 8; k8++) {
        bf16x8 hv = hp[k8];
#pragma unroll
        for (int i = 0; i < 8; i++)
            acc += bf2f((ushort)hv[i]) * W_d2[(k8 * 8 + i) * 6 + j];
    }
    out[g] = 1.f / (1.f + __expf(-acc));
}

// ---------------------------------------------------------------------------
extern "C" void kernel_launch(void* const* d_in, const int* in_sizes, int n_in,
                              void* d_out, int out_size, void* d_ws, size_t ws_size,
                              hipStream_t stream)
{
    const float* x         = (const float*)d_in[0];
    const float* edge_attr = (const float*)d_in[1];
    const float* W_ne = (const float*)d_in[2];  const float* b_ne = (const float*)d_in[3];
    const float* W_ee = (const float*)d_in[4];  const float* b_ee = (const float*)d_in[5];
    const float* W_l  = (const float*)d_in[6];  const float* b_l  = (const float*)d_in[7];
    const float* W_r  = (const float*)d_in[8];  const float* b_r  = (const float*)d_in[9];
    const float* W_e  = (const float*)d_in[10]; const float* b_e  = (const float*)d_in[11];
    const float* att  = (const float*)d_in[12];
    const float* conv_bias = (const float*)d_in[13];
    const float* W_d1 = (const float*)d_in[14]; const float* b_d1 = (const float*)d_in[15];
    const float* W_d2 = (const float*)d_in[16]; const float* b_d2 = (const float*)d_in[17];
    const int*   ei   = (const int*)d_in[18];
    float* out = (float*)d_out;

    const size_t NODE256  = (size_t)NN * HID;   // 5.12M
    const size_t NODE1024 = (size_t)NN * HO;    // 20.48M
    char* p = (char*)d_ws;
    ushort* h_bf   = (ushort*)p;  p += NODE256 * 2;    // 10.24 MB; reused as hid
    ushort* xl_bf  = (ushort*)p;  p += NODE1024 * 2;   // 40.96 MB
    ushort* xr_bf  = (ushort*)p;  p += NODE1024 * 2;   // 40.96 MB; reused as agg
    float*  lbuf4  = (float*)p;   p += (size_t)NE * HEADS * 4;
    int*    deg    = (int*)p;     p += (size_t)NN * 4;
    int*    rowptr = (int*)p;     p += (size_t)(NN + 1) * 4;
    int*    cursor = (int*)p;     p += (size_t)NN * 4;
    int*    eidx   = (int*)p;     p += (size_t)NE * 4;
    int*    srcs   = (int*)p;     p += (size_t)NE * 4;
    int*    dsts   = (int*)p;     p += (size_t)NE * 4;
    float*  biasH  = (float*)p;   p += HID * 4;
    ushort* WlT    = (ushort*)p;  p += (size_t)HO * HID * 2;   // [1024][256]
    ushort* WrT    = (ushort*)p;  p += (size_t)HO * HID * 2;
    ushort* WeT    = (ushort*)p;  p += (size_t)HO * HID * 2;
    ushort* Wd1T   = (ushort*)p;  p += (size_t)HID * HO * 2;   // [256][1024]
    if ((size_t)(p - (char*)d_ws) > ws_size) return;  // clean fail, no OOB

    ushort* agg_bf = xr_bf;   // xr dead after edge kernel
    ushort* hid_bf = h_bf;    // h dead after xl/xr GEMMs

    hipMemsetAsync(deg, 0, (size_t)NN * 4, stream);

    node_enc_kernel<<<NN, 256, 0, stream>>>(x, W_ne, b_ne, h_bf);
    biasH_kernel<<<1, 256, 0, stream>>>(conv_bias, W_d1, b_d1, biasH);

    transpose_bf16_kernel<<<dim3(HID, HO / 256), 256, 0, stream>>>(W_l,  WlT,  HID, HO);
    transpose_bf16_kernel<<<dim3(HID, HO / 256), 256, 0, stream>>>(W_r,  WrT,  HID, HO);
    transpose_bf16_kernel<<<dim3(HID, HO / 256), 256, 0, stream>>>(W_e,  WeT,  HID, HO);
    transpose_bf16_kernel<<<dim3(HO, HID / 256), 256, 0, stream>>>(W_d1, Wd1T, HO,  HID);

    hist_kernel<<<(NE + 255) / 256, 256, 0, stream>>>(ei, deg);
    scan_kernel<<<1, 1024, 0, stream>>>(deg, rowptr, cursor);
    scatter_kernel<<<(NE + 255) / 256, 256, 0, stream>>>(ei, cursor, eidx, srcs, dsts);

    const int gemmGrid = (NN + 63) / 64;     // 313

    // xl, xr: all heads in one dispatch each
    qkv_gemm_kernel<<<dim3(gemmGrid, 4), 256, 0, stream>>>(h_bf, WlT, b_l, xl_bf, NN);
    qkv_gemm_kernel<<<dim3(gemmGrid, 4), 256, 0, stream>>>(h_bf, WrT, b_r, xr_bf, NN);

    // edge logits, all heads (software-pipelined gathers)
    edge_mfma_logits_kernel<<<NE / EPB, 256, 0, stream>>>(
        edge_attr, W_ee, b_ee, WeT, b_e, att, xl_bf, xr_bf,
        eidx, srcs, dsts, lbuf4);

    // segment softmax + aggregation, all heads (writes agg into xr buffer)
    softmax_agg_kernel<<<NN, 256, 0, stream>>>(lbuf4, rowptr, srcs, xl_bf, agg_bf);

    // decoder layer 1: K=1024, fused bias+relu, bf16 out (into h buffer)
    dec_gemm_kernel<<<gemmGrid, 256, 0, stream>>>(agg_bf, Wd1T, biasH, hid_bf, NN);

    // decoder layer 2 + sigmoid
    final_kernel<<<(NN * 6 + 255) / 256, 256, 0, stream>>>(hid_bf, W_d2, b_d2, out);
}